// Round 25
// baseline (998.447 us; speedup 1.0000x reference)
//
#include <hip/hip_runtime.h>
#include <math.h>

#define NN 100000
#define NE 800000
// DIM=128, HEADS=4, CH=32

typedef __attribute__((ext_vector_type(8))) short short8;
typedef __attribute__((ext_vector_type(4))) float f32x4;
typedef __attribute__((ext_vector_type(2))) float f32x2;

__device__ __forceinline__ float bf2f(unsigned short u) {
  union { float f; unsigned int i; } x; x.i = ((unsigned int)u) << 16; return x.f;
}
__device__ __forceinline__ unsigned short f2bf(float f) {
  union { float f; unsigned int i; } x; x.f = f;
  unsigned int r = x.i + 0x7fffu + ((x.i >> 16) & 1u);
  return (unsigned short)(r >> 16);
}

// ---- HW fp8 pack/unpack (gfx950 cvt_pk instructions; self-consistent roundtrip) ----
__device__ __forceinline__ unsigned int pk4_fp8(float a, float b, float c, float d) {
  int w = __builtin_amdgcn_cvt_pk_fp8_f32(a, b, 0, false);
  w = __builtin_amdgcn_cvt_pk_fp8_f32(c, d, w, true);
  return (unsigned int)w;
}
__device__ __forceinline__ void upk4_fp8(unsigned int w, float& a, float& b, float& c, float& d) {
  f32x2 lo = __builtin_amdgcn_cvt_pk_f32_fp8((int)w, false);
  f32x2 hi = __builtin_amdgcn_cvt_pk_f32_fp8((int)w, true);
  a = lo[0]; b = lo[1]; c = hi[0]; d = hi[1];
}

// ================= CSR build =================
__global__ __launch_bounds__(256) void hist_k(const int* __restrict__ ei, int* __restrict__ deg) {
  int t = blockIdx.x * 256 + threadIdx.x;
  if (t < NE) atomicAdd(&deg[ei[NE + t]], 1);
}

__global__ __launch_bounds__(256) void scan1(const int* __restrict__ deg, int* __restrict__ bsum) {
  __shared__ int sd[256];
  const int b = blockIdx.x, t = threadIdx.x, base = b * 1024;
  int s = 0;
  #pragma unroll
  for (int i = 0; i < 4; i++) { int idx = base + t * 4 + i; if (idx < NN) s += deg[idx]; }
  sd[t] = s; __syncthreads();
  for (int off = 128; off >= 1; off >>= 1) { if (t < off) sd[t] += sd[t + off]; __syncthreads(); }
  if (t == 0) bsum[b] = sd[0];
}

__global__ __launch_bounds__(64) void scan2(int* __restrict__ bsum, int nb, int* __restrict__ rowstart) {
  const int lane = threadIdx.x;
  int v0 = (2 * lane     < nb) ? bsum[2 * lane]     : 0;
  int v1 = (2 * lane + 1 < nb) ? bsum[2 * lane + 1] : 0;
  const int s = v0 + v1;
  int inc = s;
  #pragma unroll
  for (int off = 1; off < 64; off <<= 1) {
    int o = __shfl_up(inc, off, 64);
    if (lane >= off) inc += o;
  }
  const int excl = inc - s;
  if (2 * lane     < nb) bsum[2 * lane]     = excl;
  if (2 * lane + 1 < nb) bsum[2 * lane + 1] = excl + v0;
  if (lane == 63) rowstart[NN] = inc;
}

__global__ __launch_bounds__(256) void scan3(const int* __restrict__ deg, const int* __restrict__ bsum,
                                             int* __restrict__ rowstart, int* __restrict__ cursor) {
  __shared__ int sd[256];
  const int b = blockIdx.x, t = threadIdx.x, base = b * 1024;
  int vals[4]; int s = 0;
  #pragma unroll
  for (int i = 0; i < 4; i++) { int idx = base + t * 4 + i; vals[i] = (idx < NN) ? deg[idx] : 0; s += vals[i]; }
  sd[t] = s; __syncthreads();
  for (int off = 1; off < 256; off <<= 1) {
    int add = (t >= off) ? sd[t - off] : 0;
    __syncthreads();
    sd[t] += add;
    __syncthreads();
  }
  const int excl = sd[t] - s;
  int run = bsum[b] + excl;
  #pragma unroll
  for (int i = 0; i < 4; i++) {
    int idx = base + t * 4 + i;
    if (idx < NN) { rowstart[idx] = run; cursor[idx] = run; run += vals[i]; }
  }
}

// srcs[pos] = src node; eids[pos] = edge id
__global__ __launch_bounds__(256) void scatter_k(const int* __restrict__ ei, int* __restrict__ cursor,
                                                 int* __restrict__ srcs, int* __restrict__ eids) {
  int t = blockIdx.x * 256 + threadIdx.x;
  if (t >= NE) return;
  int dst = ei[NE + t];
  int pos = atomicAdd(&cursor[dst], 1);
  srcs[pos] = ei[t];
  eids[pos] = t;
}

// ================= weight prep =================
__global__ __launch_bounds__(256) void conv_w(
    const float* __restrict__ Wq, const float* __restrict__ Wk, const float* __restrict__ Wv,
    const float* __restrict__ Ws, const float* __restrict__ We, const float* __restrict__ Wo,
    unsigned short* __restrict__ wT)
{
  int idx = blockIdx.x * 256 + threadIdx.x;   // 11*16384 total
  int m = idx >> 14;
  int r = idx & 16383;
  int n = r >> 7, kk = r & 127;
  const float* src;
  switch (m) {
    case 0: src = Wq; break;
    case 1: src = Wk; break;
    case 2: src = Wv; break;
    case 3: src = Ws; break;
    case 4: src = Wq + 16384; break;
    case 5: src = Wk + 16384; break;
    case 6: src = Wv + 16384; break;
    case 7: src = Ws + 16384; break;
    case 8: src = We; break;
    case 9: src = We + 16384; break;
    default: src = Wo; break;
  }
  wT[idx] = f2bf(src[(size_t)kk * 128 + n]);
}

// ================= shared GEMM body =================
// Per-output formats F0,F1: 1 = fp8 (HW cvt, 128B rows), 0 = bf16 (256B rows).
// Unified f32 LDS transpose strip (144 B row stride).
template<int F0, int F1>
__device__ __forceinline__ void gemm_body(
    const void* Ap, int abf16, const unsigned short* wT, int s0, int s1,
    const float* bias0, const float* bias1,
    void* o0v, void* o1v, int M, int blk,
    unsigned short* As, unsigned char* OsRaw)
{
  const int wave = threadIdx.x >> 6, lane = threadIdx.x & 63;
  const int l15 = lane & 15, g = lane >> 4;
  const int colf = wave * 32;
  const int rb = blk * 64;
  unsigned char* strip = OsRaw + wave * (16 * 144);
  const bool do1 = (o1v != nullptr);
  const bool hasbias = (bias0 != nullptr);

  short8 wf[2][2][4];
  const int slots[2] = { s0, s1 };
  #pragma unroll
  for (int m = 0; m < 2; ++m) {
    const unsigned short* wp = wT + (size_t)slots[m] * 16384;
    #pragma unroll
    for (int cb = 0; cb < 2; ++cb) {
      const int col = colf + cb * 16 + l15;
      #pragma unroll
      for (int kt = 0; kt < 4; ++kt)
        wf[m][cb][kt] = *(const short8*)(wp + (size_t)col * 128 + kt * 32 + g * 8);
    }
  }
  float bia[2][2][4];
  if (hasbias) {
    const float* bp[2] = { bias0, bias1 };
    #pragma unroll
    for (int m = 0; m < 2; ++m)
      #pragma unroll
      for (int cb = 0; cb < 2; ++cb)
        #pragma unroll
        for (int j = 0; j < 4; ++j)
          bia[m][cb][j] = bp[m][colf + cb * 16 + g * 4 + j];
  } else {
    #pragma unroll
    for (int m = 0; m < 2; ++m)
      #pragma unroll
      for (int cb = 0; cb < 2; ++cb)
        #pragma unroll
        for (int j = 0; j < 4; ++j)
          bia[m][cb][j] = 0.f;
  }

  // --- cooperative stage, lane-contiguous global reads ---
  if (abf16) {
    #pragma unroll
    for (int it = 0; it < 4; ++it) {
      const int c = it * 256 + threadIdx.x;
      const int row = c >> 4, cw = c & 15;
      const int gr = rb + row;
      const int ar = (gr < M) ? gr : (M - 1);
      short8 vch = *(const short8*)((const unsigned short*)Ap + (size_t)ar * 128 + cw * 8);
      *(short8*)(As + row * 136 + cw * 8) = vch;
    }
  } else {
    #pragma unroll
    for (int it = 0; it < 8; ++it) {
      const int c = it * 256 + threadIdx.x;
      const int row = c >> 5, cw = c & 31;
      const int gr = rb + row;
      const int ar = (gr < M) ? gr : (M - 1);
      const float4 f = *(const float4*)((const float*)Ap + (size_t)ar * 128 + cw * 4);
      uint2 pk;
      pk.x = (unsigned int)f2bf(f.x) | ((unsigned int)f2bf(f.y) << 16);
      pk.y = (unsigned int)f2bf(f.z) | ((unsigned int)f2bf(f.w) << 16);
      *(uint2*)(As + row * 136 + cw * 4) = pk;
    }
  }
  __syncthreads();

  const int srow = rb + l15;

  #pragma unroll
  for (int rg = 0; rg < 4; ++rg) {
    const int row = rg * 16 + l15;
    short8 a[4];
    #pragma unroll
    for (int kt = 0; kt < 4; ++kt)
      a[kt] = *(const short8*)(As + row * 136 + kt * 32 + g * 8);

    const int r = srow + rg * 16;

    #pragma unroll
    for (int m = 0; m < 2; ++m) {
      if (m == 1 && !do1) break;
      #pragma unroll
      for (int cb = 0; cb < 2; ++cb) {
        f32x4 acc; acc[0] = 0.f; acc[1] = 0.f; acc[2] = 0.f; acc[3] = 0.f;
        #pragma unroll
        for (int kt = 0; kt < 4; ++kt)
          acc = __builtin_amdgcn_mfma_f32_16x16x32_bf16(wf[m][cb][kt], a[kt], acc, 0, 0, 0);
        acc[0] += bia[m][cb][0];
        acc[1] += bia[m][cb][1];
        acc[2] += bia[m][cb][2];
        acc[3] += bia[m][cb][3];
        *(f32x4*)(strip + l15 * 144 + (cb * 16 + g * 4) * 4) = acc;
      }
      if (r < M) {
        const f32x4 lo = *(const f32x4*)(strip + l15 * 144 + (g * 8) * 4);
        const f32x4 hi = *(const f32x4*)(strip + l15 * 144 + (g * 8 + 4) * 4);
        const int fmt = (m == 0) ? F0 : F1;
        if (fmt) {
          uint2 pk8;
          pk8.x = pk4_fp8(lo[0], lo[1], lo[2], lo[3]);
          pk8.y = pk4_fp8(hi[0], hi[1], hi[2], hi[3]);
          unsigned char* op8 = (unsigned char*)((m == 0) ? o0v : o1v);
          *(uint2*)(op8 + (size_t)r * 128 + colf + g * 8) = pk8;
        } else {
          short8 vv;
          vv[0] = (short)f2bf(lo[0]); vv[1] = (short)f2bf(lo[1]);
          vv[2] = (short)f2bf(lo[2]); vv[3] = (short)f2bf(lo[3]);
          vv[4] = (short)f2bf(hi[0]); vv[5] = (short)f2bf(hi[1]);
          vv[6] = (short)f2bf(hi[2]); vv[7] = (short)f2bf(hi[3]);
          unsigned short* op = (unsigned short*)((m == 0) ? o0v : o1v);
          *(short8*)(op + (size_t)r * 128 + colf + g * 8) = vv;
        }
      }
    }
  }
}

// ================= merged launch: edge dual-GEMM (fp8) + L1 q(bf16)/k(fp8) + v(fp8)/xr(bf16) =================
__global__ __launch_bounds__(256, 6) void mega_l1(
    const float* __restrict__ ea, const float* __restrict__ x, const unsigned short* __restrict__ wT,
    const float* __restrict__ bq, const float* __restrict__ bk,
    const float* __restrict__ bv, const float* __restrict__ bs,
    unsigned char* __restrict__ e0, unsigned char* e1,
    unsigned short* __restrict__ q, unsigned char* __restrict__ k8,
    unsigned char* __restrict__ v8, unsigned short* __restrict__ xr,
    int ntile_e, int ntile_n)
{
  __shared__ __align__(16) unsigned short As[64 * 136];
  __shared__ __align__(16) unsigned char OsRaw[4 * 16 * 144];
  const int b = blockIdx.x;
  if (b < ntile_e) {
    gemm_body<1, 1>(ea, 0, wT, 8, 9, nullptr, nullptr, e0, e1, NE, b, As, OsRaw);
  } else if (b < ntile_e + ntile_n) {
    gemm_body<0, 1>(x, 0, wT, 0, 1, bq, bk, q, k8, NN, b - ntile_e, As, OsRaw);
  } else {
    gemm_body<1, 0>(x, 0, wT, 2, 3, bv, bs, v8, xr, NN, b - ntile_e - ntile_n, As, OsRaw);
  }
}

// ================= merged launch: both L2 qkvs GEMMs (bf16 input h1) =================
__global__ __launch_bounds__(256, 6) void mega_l2(
    const unsigned short* __restrict__ h1, const unsigned short* __restrict__ wT,
    const float* __restrict__ bq, const float* __restrict__ bk,
    const float* __restrict__ bv, const float* __restrict__ bs,
    unsigned short* __restrict__ q, unsigned char* __restrict__ k8,
    unsigned char* __restrict__ v8, unsigned short* __restrict__ xr,
    int ntile_n)
{
  __shared__ __align__(16) unsigned short As[64 * 136];
  __shared__ __align__(16) unsigned char OsRaw[4 * 16 * 144];
  const int b = blockIdx.x;
  if (b < ntile_n) {
    gemm_body<0, 1>(h1, 1, wT, 4, 5, bq, bk, q, k8, NN, b, As, OsRaw);
  } else {
    gemm_body<1, 0>(h1, 1, wT, 6, 7, bv, bs, v8, xr, NN, b - ntile_n, As, OsRaw);
  }
}

// ================= single edge GEMM (non-dual fallback, fp8 out, linear) =================
__global__ __launch_bounds__(256, 6) void edge_single(
    const float* __restrict__ ea, const unsigned short* __restrict__ wT, int slot,
    unsigned char* __restrict__ e0)
{
  __shared__ __align__(16) unsigned short As[64 * 136];
  __shared__ __align__(16) unsigned char OsRaw[4 * 16 * 144];
  gemm_body<1, 1>(ea, 0, wT, slot, slot, nullptr, nullptr, e0, nullptr, NE, blockIdx.x, As, OsRaw);
}

// ================= final GEMM + fused gate + epilogue (f32 out), 64 rows/block =================
__global__ __launch_bounds__(256, 2) void final_rs(
    const unsigned short* __restrict__ A, const unsigned short* __restrict__ wp,
    const float* __restrict__ bo, const float* __restrict__ xin,
    const float* __restrict__ Wg, const float* __restrict__ bg,
    float* __restrict__ out, int M)
{
  __shared__ float gl[4][64];
  __shared__ float grow_s[64];
  const int wave = threadIdx.x >> 6, lane = threadIdx.x & 63;
  const int l15 = lane & 15, g = lane >> 4;
  const int colf = wave * 32;
  const int rb = blockIdx.x * 64;

  short8 wf[2][4];
  #pragma unroll
  for (int cb = 0; cb < 2; ++cb) {
    const int col = colf + cb * 16 + l15;
    #pragma unroll
    for (int kt = 0; kt < 4; ++kt)
      wf[cb][kt] = *(const short8*)(wp + (size_t)col * 128 + kt * 32 + g * 8);
  }
  float bia[2][4], wgf[2][4];
  #pragma unroll
  for (int cb = 0; cb < 2; ++cb)
    #pragma unroll
    for (int j = 0; j < 4; ++j) {
      bia[cb][j] = bo[colf + cb * 16 + g * 4 + j];
      wgf[cb][j] = Wg[colf + cb * 16 + g * 4 + j];
    }

  f32x4 accs[4][2];
  float4 xv[4][2];

  #pragma unroll
  for (int rg = 0; rg < 4; ++rg) {
    const int r = rb + rg * 16 + l15;
    const int ar = (r < M) ? r : (M - 1);
    short8 a[4];
    #pragma unroll
    for (int kt = 0; kt < 4; ++kt)
      a[kt] = *(const short8*)(A + (size_t)ar * 128 + kt * 32 + g * 8);

    float part = 0.f;
    #pragma unroll
    for (int cb = 0; cb < 2; ++cb) {
      f32x4 acc; acc[0] = 0.f; acc[1] = 0.f; acc[2] = 0.f; acc[3] = 0.f;
      #pragma unroll
      for (int kt = 0; kt < 4; ++kt)
        acc = __builtin_amdgcn_mfma_f32_16x16x32_bf16(wf[cb][kt], a[kt], acc, 0, 0, 0);
      accs[rg][cb] = acc;
      const int c0 = colf + cb * 16 + g * 4;
      const float4 x4 = *(const float4*)(xin + (size_t)ar * 128 + c0);
      xv[rg][cb] = x4;
      part += x4.x * wgf[cb][0] + x4.y * wgf[cb][1] + x4.z * wgf[cb][2] + x4.w * wgf[cb][3];
    }
    part += __shfl_xor(part, 16, 64);
    part += __shfl_xor(part, 32, 64);
    if (g == 0) gl[wave][rg * 16 + l15] = part;
  }
  __syncthreads();
  if (threadIdx.x < 64) {
    const float s = gl[0][threadIdx.x] + gl[1][threadIdx.x] + gl[2][threadIdx.x] + gl[3][threadIdx.x] + bg[0];
    grow_s[threadIdx.x] = 1.f / (1.f + expf(-s));
  }
  __syncthreads();

  #pragma unroll
  for (int rg = 0; rg < 4; ++rg) {
    const int r = rb + rg * 16 + l15;
    if (r < M) {
      const float gr = grow_s[rg * 16 + l15];
      #pragma unroll
      for (int cb = 0; cb < 2; ++cb) {
        const int c0 = colf + cb * 16 + g * 4;
        const float4 x4 = xv[rg][cb];
        const f32x4 acc = accs[rg][cb];
        float4 res;
        res.x = gr * x4.x + (1.f - gr) * (acc[0] + bia[cb][0]);
        res.y = gr * x4.y + (1.f - gr) * (acc[1] + bia[cb][1]);
        res.z = gr * x4.z + (1.f - gr) * (acc[2] + bia[cb][2]);
        res.w = gr * x4.w + (1.f - gr) * (acc[3] + bia[cb][3]);
        *(float4*)(out + (size_t)r * 128 + c0) = res;
      }
    }
  }
}

// ================= fused CSR attention, 2 nodes/wave; k,v,e all fp8 (HW unpack) =================
__global__ __launch_bounds__(256) void csr_attn(
    const int* __restrict__ rowstart, const int* __restrict__ srcs, const int* __restrict__ eids,
    const unsigned char* __restrict__ e,    // edge-order fp8, 128 B/row
    const unsigned short* __restrict__ q,   // bf16
    const unsigned char* __restrict__ k8,   // fp8, 128 B/row
    const unsigned char* __restrict__ v8,   // fp8, 128 B/row
    const unsigned short* __restrict__ xr,
    const float* __restrict__ Wb, const float* __restrict__ lng, const float* __restrict__ lnb,
    const unsigned short* __restrict__ prev, unsigned short* __restrict__ hout)
{
  const int n = blockIdx.x * 8 + (threadIdx.x >> 5);    // half-wave per node
  if (n >= NN) return;
  const int lh = threadIdx.x & 31;                      // lane within half
  const int d0 = lh * 4;                                // 4 dims per lane
  const size_t base = (size_t)n * 128 + d0;

  const uint2 qp = *(const uint2*)(q + base);
  const float q0 = bf2f(qp.x & 0xffff), q1 = bf2f(qp.x >> 16);
  const float q2 = bf2f(qp.y & 0xffff), q3 = bf2f(qp.y >> 16);

  float a0 = 0.f, a1 = 0.f, a2 = 0.f, a3 = 0.f, den = 0.f;
  const int s = rowstart[n], eend = rowstart[n + 1];
  const float scale = 0.17677669529663687f;   // 1/sqrt(32)

  int pos = s;
  for (; pos + 3 < eend; pos += 4) {
    const int s0_ = srcs[pos], s1_ = srcs[pos + 1], s2_ = srcs[pos + 2], s3_ = srcs[pos + 3];
    const int t0_ = eids[pos], t1_ = eids[pos + 1], t2_ = eids[pos + 2], t3_ = eids[pos + 3];
    const unsigned int kp0 = *(const unsigned int*)(k8 + (size_t)s0_ * 128 + d0);
    const unsigned int kp1 = *(const unsigned int*)(k8 + (size_t)s1_ * 128 + d0);
    const unsigned int kp2 = *(const unsigned int*)(k8 + (size_t)s2_ * 128 + d0);
    const unsigned int kp3 = *(const unsigned int*)(k8 + (size_t)s3_ * 128 + d0);
    const unsigned int ep0 = *(const unsigned int*)(e + (size_t)t0_ * 128 + d0);
    const unsigned int ep1 = *(const unsigned int*)(e + (size_t)t1_ * 128 + d0);
    const unsigned int ep2 = *(const unsigned int*)(e + (size_t)t2_ * 128 + d0);
    const unsigned int ep3 = *(const unsigned int*)(e + (size_t)t3_ * 128 + d0);
    const unsigned int vp0 = *(const unsigned int*)(v8 + (size_t)s0_ * 128 + d0);
    const unsigned int vp1 = *(const unsigned int*)(v8 + (size_t)s1_ * 128 + d0);
    const unsigned int vp2 = *(const unsigned int*)(v8 + (size_t)s2_ * 128 + d0);
    const unsigned int vp3 = *(const unsigned int*)(v8 + (size_t)s3_ * 128 + d0);

    float e00, e01, e02, e03, e10, e11, e12, e13;
    float e20, e21, e22, e23, e30, e31, e32, e33;
    upk4_fp8(ep0, e00, e01, e02, e03);
    upk4_fp8(ep1, e10, e11, e12, e13);
    upk4_fp8(ep2, e20, e21, e22, e23);
    upk4_fp8(ep3, e30, e31, e32, e33);

    float k00, k01, k02, k03, k10, k11, k12, k13;
    float k20, k21, k22, k23, k30, k31, k32, k33;
    upk4_fp8(kp0, k00, k01, k02, k03);
    upk4_fp8(kp1, k10, k11, k12, k13);
    upk4_fp8(kp2, k20, k21, k22, k23);
    upk4_fp8(kp3, k30, k31, k32, k33);

    float d0_ = q0 * (k00 + e00) + q1 * (k01 + e01) + q2 * (k02 + e02) + q3 * (k03 + e03);
    float d1_ = q0 * (k10 + e10) + q1 * (k11 + e11) + q2 * (k12 + e12) + q3 * (k13 + e13);
    float d2_ = q0 * (k20 + e20) + q1 * (k21 + e21) + q2 * (k22 + e22) + q3 * (k23 + e23);
    float d3_ = q0 * (k30 + e30) + q1 * (k31 + e31) + q2 * (k32 + e32) + q3 * (k33 + e33);

    d0_ += __shfl_xor(d0_, 1, 64); d1_ += __shfl_xor(d1_, 1, 64);
    d2_ += __shfl_xor(d2_, 1, 64); d3_ += __shfl_xor(d3_, 1, 64);
    d0_ += __shfl_xor(d0_, 2, 64); d1_ += __shfl_xor(d1_, 2, 64);
    d2_ += __shfl_xor(d2_, 2, 64); d3_ += __shfl_xor(d3_, 2, 64);
    d0_ += __shfl_xor(d0_, 4, 64); d1_ += __shfl_xor(d1_, 4, 64);
    d2_ += __shfl_xor(d2_, 4, 64); d3_ += __shfl_xor(d3_, 4, 64);

    const float p0 = expf(d0_ * scale);
    const float p1 = expf(d1_ * scale);
    const float p2 = expf(d2_ * scale);
    const float p3 = expf(d3_ * scale);

    float w00, w01, w02, w03, w10, w11, w12, w13;
    float w20, w21, w22, w23, w30, w31, w32, w33;
    upk4_fp8(vp0, w00, w01, w02, w03);
    upk4_fp8(vp1, w10, w11, w12, w13);
    upk4_fp8(vp2, w20, w21, w22, w23);
    upk4_fp8(vp3, w30, w31, w32, w33);

    a0 += p0 * (w00 + e00) + p1 * (w10 + e10) + p2 * (w20 + e20) + p3 * (w30 + e30);
    a1 += p0 * (w01 + e01) + p1 * (w11 + e11) + p2 * (w21 + e21) + p3 * (w31 + e31);
    a2 += p0 * (w02 + e02) + p1 * (w12 + e12) + p2 * (w22 + e22) + p3 * (w32 + e32);
    a3 += p0 * (w03 + e03) + p1 * (w13 + e13) + p2 * (w23 + e23) + p3 * (w33 + e33);
    den += (p0 + p1) + (p2 + p3);
  }
  for (; pos < eend; ++pos) {
    const int sA = srcs[pos];
    const int tA = eids[pos];
    const unsigned int kpA = *(const unsigned int*)(k8 + (size_t)sA * 128 + d0);
    const unsigned int epA = *(const unsigned int*)(e + (size_t)tA * 128 + d0);
    const unsigned int vpA = *(const unsigned int*)(v8 + (size_t)sA * 128 + d0);
    float eA0, eA1, eA2, eA3, kA0, kA1, kA2, kA3, wA0, wA1, wA2, wA3;
    upk4_fp8(epA, eA0, eA1, eA2, eA3);
    upk4_fp8(kpA, kA0, kA1, kA2, kA3);
    upk4_fp8(vpA, wA0, wA1, wA2, wA3);
    float dA = q0 * (kA0 + eA0) + q1 * (kA1 + eA1) + q2 * (kA2 + eA2) + q3 * (kA3 + eA3);
    dA += __shfl_xor(dA, 1, 64);
    dA += __shfl_xor(dA, 2, 64);
    dA += __shfl_xor(dA, 4, 64);
    const float pA = expf(dA * scale);
    a0 += pA * (wA0 + eA0);
    a1 += pA * (wA1 + eA1);
    a2 += pA * (wA2 + eA2);
    a3 += pA * (wA3 + eA3);
    den += pA;
  }

  const float dinv = 1.f / (den + 1e-16f);
  const float o0 = a0 * dinv, o1 = a1 * dinv, o2 = a2 * dinv, o3 = a3 * dinv;

  const uint2 xp = *(const uint2*)(xr + base);
  const float x0 = bf2f(xp.x & 0xffff), x1 = bf2f(xp.x >> 16);
  const float x2 = bf2f(xp.y & 0xffff), x3 = bf2f(xp.y >> 16);

  const float4 wb0 = *(const float4*)(Wb + d0);
  const float4 wb1 = *(const float4*)(Wb + 128 + d0);
  const float4 wb2 = *(const float4*)(Wb + 256 + d0);
  float sb = o0 * wb0.x + o1 * wb0.y + o2 * wb0.z + o3 * wb0.w
           + x0 * wb1.x + x1 * wb1.y + x2 * wb1.z + x3 * wb1.w
           + (o0 - x0) * wb2.x + (o1 - x1) * wb2.y + (o2 - x2) * wb2.z + (o3 - x3) * wb2.w;
  #pragma unroll
  for (int off = 16; off >= 1; off >>= 1) sb += __shfl_xor(sb, off, 64);
  const float beta = 1.f / (1.f + expf(-sb));

  float y0 = beta * x0 + (1.f - beta) * o0;
  float y1 = beta * x1 + (1.f - beta) * o1;
  float y2 = beta * x2 + (1.f - beta) * o2;
  float y3 = beta * x3 + (1.f - beta) * o3;
  y0 = 0.5f * y0 * (1.f + erff(y0 * 0.7071067811865475f));
  y1 = 0.5f * y1 * (1.f + erff(y1 * 0.7071067811865475f));
  y2 = 0.5f * y2 * (1.f + erff(y2 * 0.7071067811865475f));
  y3 = 0.5f * y3 * (1.f + erff(y3 * 0.7071067811865475f));

  float mu = (y0 + y1) + (y2 + y3);
  #pragma unroll
  for (int off = 16; off >= 1; off >>= 1) mu += __shfl_xor(mu, off, 64);
  mu *= (1.f / 128.f);
  const float dv0 = y0 - mu, dv1 = y1 - mu, dv2 = y2 - mu, dv3 = y3 - mu;
  float var = (dv0 * dv0 + dv1 * dv1) + (dv2 * dv2 + dv3 * dv3);
  #pragma unroll
  for (int off = 16; off >= 1; off >>= 1) var += __shfl_xor(var, off, 64);
  var *= (1.f / 128.f);
  const float rs = rsqrtf(var + 1e-5f);

  const float4 lg = *(const float4*)(lng + d0);
  const float4 lb = *(const float4*)(lnb + d0);
  float h0 = dv0 * rs * lg.x + lb.x;
  float h1 = dv1 * rs * lg.y + lb.y;
  float h2 = dv2 * rs * lg.z + lb.z;
  float h3 = dv3 * rs * lg.w + lb.w;
  if (prev) {
    const uint2 pp = *(const uint2*)(prev + base);
    h0 += bf2f(pp.x & 0xffff); h1 += bf2f(pp.x >> 16);
    h2 += bf2f(pp.y & 0xffff); h3 += bf2f(pp.y >> 16);
  }
  uint2 packed;
  packed.x = (unsigned int)f2bf(h0) | ((unsigned int)f2bf(h1) << 16);
  packed.y = (unsigned int)f2bf(h2) | ((unsigned int)f2bf(h3) << 16);
  *(uint2*)(hout + base) = packed;
}

extern "C" void kernel_launch(void* const* d_in, const int* in_sizes, int n_in,
                              void* d_out, int out_size, void* d_ws, size_t ws_size,
                              hipStream_t stream)
{
  const float* x  = (const float*)d_in[0];
  const int*   ei = (const int*)d_in[1];
  const float* ea = (const float*)d_in[2];
  const float* Wq = (const float*)d_in[3];
  const float* bq = (const float*)d_in[4];
  const float* Wk = (const float*)d_in[5];
  const float* bk = (const float*)d_in[6];
  const float* Wv = (const float*)d_in[7];
  const float* bv = (const float*)d_in[8];
  const float* We = (const float*)d_in[9];
  const float* Ws = (const float*)d_in[10];
  const float* bs = (const float*)d_in[11];
  const float* Wb = (const float*)d_in[12];
  const float* lng= (const float*)d_in[13];
  const float* lnb= (const float*)d_in[14];
  const float* Wo = (const float*)d_in[15];
  const float* bo = (const float*)d_in[16];
  const float* Wg = (const float*)d_in[17];
  const float* bg = (const float*)d_in[18];
  float* outp = (float*)d_out;

  char* p = (char*)d_ws;
  auto take = [&](size_t b) -> char* { char* r = p; p += (b + 255) & ~(size_t)255; return r; };
  unsigned short* wT = (unsigned short*)take((size_t)11 * 16384 * 2);
  unsigned short* q  = (unsigned short*)take((size_t)NN * 128 * 2);
  unsigned char* k8  = (unsigned char*)take((size_t)NN * 128);
  unsigned char* v8  = (unsigned char*)take((size_t)NN * 128);
  unsigned short* xr = (unsigned short*)take((size_t)NN * 128 * 2);
  unsigned short* h1 = (unsigned short*)take((size_t)NN * 128 * 2);
  unsigned short* hs = (unsigned short*)take((size_t)NN * 128 * 2);
  int* deg      = (int*)take((size_t)NN * 4);
  int* rowstart = (int*)take((size_t)(NN + 1) * 4);
  int* cursor   = (int*)take((size_t)NN * 4);
  int* bsum     = (int*)take((size_t)128 * 4);
  int* srcs     = (int*)take((size_t)NE * 4);
  int* eids     = (int*)take((size_t)NE * 4);
  unsigned char* e0 = (unsigned char*)take((size_t)NE * 128);     // fp8: 1 B/elem
  size_t used = (size_t)(p - (char*)d_ws);
  const bool dual = (used + (size_t)NE * 128 <= ws_size);
  unsigned char* e1 = dual ? (unsigned char*)take((size_t)NE * 128) : e0;

  const int SCAN_BLOCKS = (NN + 1023) / 1024;   // 98
  const int NTILE_E  = (NE + 63) / 64;          // 12500
  const int NTILE_N  = (NN + 63) / 64;          // 1563
  const int NTILE_A  = (NN + 7) / 8;            // 12500

  // ---- CSR build ----
  hipMemsetAsync(deg, 0, (size_t)NN * 4, stream);
  hist_k<<<(NE + 255) / 256, 256, 0, stream>>>(ei, deg);
  scan1<<<SCAN_BLOCKS, 256, 0, stream>>>(deg, bsum);
  scan2<<<1, 64, 0, stream>>>(bsum, SCAN_BLOCKS, rowstart);
  scan3<<<SCAN_BLOCKS, 256, 0, stream>>>(deg, bsum, rowstart, cursor);
  scatter_k<<<(NE + 255) / 256, 256, 0, stream>>>(ei, cursor, srcs, eids);

  // ---- weights ----
  conv_w<<<704, 256, 0, stream>>>(Wq, Wk, Wv, Ws, We, Wo, wT);

  // ---- merged: edge projection (linear fp8) + L1 qkvs (k,v fp8) ----
  mega_l1<<<NTILE_E + 2 * NTILE_N, 256, 0, stream>>>(
      ea, x, wT, bq, bk, bv, bs,
      e0, dual ? e1 : nullptr, q, k8, v8, xr, NTILE_E, NTILE_N);
  csr_attn<<<NTILE_A, 256, 0, stream>>>(rowstart, srcs, eids, e0, q, k8, v8, xr, Wb, lng, lnb, nullptr, h1);

  // ---- layer 2 ----
  if (!dual) edge_single<<<NTILE_E, 256, 0, stream>>>(ea, wT, 9, e0);
  mega_l2<<<2 * NTILE_N, 256, 0, stream>>>(h1, wT, bq + 128, bk + 128, bv + 128, bs + 128, q, k8, v8, xr, NTILE_N);
  csr_attn<<<NTILE_A, 256, 0, stream>>>(rowstart, srcs, eids, dual ? e1 : e0, q, k8, v8, xr,
                                        Wb + 384, lng + 128, lnb + 128, h1, hs);

  // ---- final (gate fused) ----
  final_rs<<<NTILE_N, 256, 0, stream>>>(hs, wT + (size_t)10 * 16384, bo, x, Wg, bg, outp, NN);
}

// Round 26
// 556.869 us; speedup vs baseline: 1.7930x; 1.7930x over previous
//
#include <hip/hip_runtime.h>
#include <math.h>

#define NN 100000
#define NE 800000
// DIM=128, HEADS=4, CH=32

typedef __attribute__((ext_vector_type(8))) short short8;
typedef __attribute__((ext_vector_type(4))) float f32x4;
typedef __attribute__((ext_vector_type(2))) float f32x2;

__device__ __forceinline__ float bf2f(unsigned short u) {
  union { float f; unsigned int i; } x; x.i = ((unsigned int)u) << 16; return x.f;
}
__device__ __forceinline__ unsigned short f2bf(float f) {
  union { float f; unsigned int i; } x; x.f = f;
  unsigned int r = x.i + 0x7fffu + ((x.i >> 16) & 1u);
  return (unsigned short)(r >> 16);
}

// ---- HW fp8 pack/unpack (gfx950 cvt_pk instructions; self-consistent roundtrip) ----
__device__ __forceinline__ unsigned int pk4_fp8(float a, float b, float c, float d) {
  int w = __builtin_amdgcn_cvt_pk_fp8_f32(a, b, 0, false);
  w = __builtin_amdgcn_cvt_pk_fp8_f32(c, d, w, true);
  return (unsigned int)w;
}
__device__ __forceinline__ void upk4_fp8(unsigned int w, float& a, float& b, float& c, float& d) {
  f32x2 lo = __builtin_amdgcn_cvt_pk_f32_fp8((int)w, false);
  f32x2 hi = __builtin_amdgcn_cvt_pk_f32_fp8((int)w, true);
  a = lo[0]; b = lo[1]; c = hi[0]; d = hi[1];
}

// ================= CSR build =================
__global__ __launch_bounds__(256) void hist_k(const int* __restrict__ ei, int* __restrict__ deg) {
  int t = blockIdx.x * 256 + threadIdx.x;
  if (t < NE) atomicAdd(&deg[ei[NE + t]], 1);
}

__global__ __launch_bounds__(256) void scan1(const int* __restrict__ deg, int* __restrict__ bsum) {
  __shared__ int sd[256];
  const int b = blockIdx.x, t = threadIdx.x, base = b * 1024;
  int s = 0;
  #pragma unroll
  for (int i = 0; i < 4; i++) { int idx = base + t * 4 + i; if (idx < NN) s += deg[idx]; }
  sd[t] = s; __syncthreads();
  for (int off = 128; off >= 1; off >>= 1) { if (t < off) sd[t] += sd[t + off]; __syncthreads(); }
  if (t == 0) bsum[b] = sd[0];
}

__global__ __launch_bounds__(64) void scan2(int* __restrict__ bsum, int nb, int* __restrict__ rowstart) {
  const int lane = threadIdx.x;
  int v0 = (2 * lane     < nb) ? bsum[2 * lane]     : 0;
  int v1 = (2 * lane + 1 < nb) ? bsum[2 * lane + 1] : 0;
  const int s = v0 + v1;
  int inc = s;
  #pragma unroll
  for (int off = 1; off < 64; off <<= 1) {
    int o = __shfl_up(inc, off, 64);
    if (lane >= off) inc += o;
  }
  const int excl = inc - s;
  if (2 * lane     < nb) bsum[2 * lane]     = excl;
  if (2 * lane + 1 < nb) bsum[2 * lane + 1] = excl + v0;
  if (lane == 63) rowstart[NN] = inc;
}

__global__ __launch_bounds__(256) void scan3(const int* __restrict__ deg, const int* __restrict__ bsum,
                                             int* __restrict__ rowstart, int* __restrict__ cursor) {
  __shared__ int sd[256];
  const int b = blockIdx.x, t = threadIdx.x, base = b * 1024;
  int vals[4]; int s = 0;
  #pragma unroll
  for (int i = 0; i < 4; i++) { int idx = base + t * 4 + i; vals[i] = (idx < NN) ? deg[idx] : 0; s += vals[i]; }
  sd[t] = s; __syncthreads();
  for (int off = 1; off < 256; off <<= 1) {
    int add = (t >= off) ? sd[t - off] : 0;
    __syncthreads();
    sd[t] += add;
    __syncthreads();
  }
  const int excl = sd[t] - s;
  int run = bsum[b] + excl;
  #pragma unroll
  for (int i = 0; i < 4; i++) {
    int idx = base + t * 4 + i;
    if (idx < NN) { rowstart[idx] = run; cursor[idx] = run; run += vals[i]; }
  }
}

// srcs[pos] = src node; eids[pos] = edge id
__global__ __launch_bounds__(256) void scatter_k(const int* __restrict__ ei, int* __restrict__ cursor,
                                                 int* __restrict__ srcs, int* __restrict__ eids) {
  int t = blockIdx.x * 256 + threadIdx.x;
  if (t >= NE) return;
  int dst = ei[NE + t];
  int pos = atomicAdd(&cursor[dst], 1);
  srcs[pos] = ei[t];
  eids[pos] = t;
}

// ================= weight prep =================
__global__ __launch_bounds__(256) void conv_w(
    const float* __restrict__ Wq, const float* __restrict__ Wk, const float* __restrict__ Wv,
    const float* __restrict__ Ws, const float* __restrict__ We, const float* __restrict__ Wo,
    unsigned short* __restrict__ wT)
{
  int idx = blockIdx.x * 256 + threadIdx.x;   // 11*16384 total
  int m = idx >> 14;
  int r = idx & 16383;
  int n = r >> 7, kk = r & 127;
  const float* src;
  switch (m) {
    case 0: src = Wq; break;
    case 1: src = Wk; break;
    case 2: src = Wv; break;
    case 3: src = Ws; break;
    case 4: src = Wq + 16384; break;
    case 5: src = Wk + 16384; break;
    case 6: src = Wv + 16384; break;
    case 7: src = Ws + 16384; break;
    case 8: src = We; break;
    case 9: src = We + 16384; break;
    default: src = Wo; break;
  }
  wT[idx] = f2bf(src[(size_t)kk * 128 + n]);
}

// ================= shared GEMM body =================
// Per-output formats F0,F1: 1 = fp8 (HW cvt, 128B rows), 0 = bf16 (256B rows).
// Unified f32 LDS transpose strip (144 B row stride).
template<int F0, int F1>
__device__ __forceinline__ void gemm_body(
    const void* Ap, int abf16, const unsigned short* wT, int s0, int s1,
    const float* bias0, const float* bias1,
    void* o0v, void* o1v, int M, int blk,
    unsigned short* As, unsigned char* OsRaw)
{
  const int wave = threadIdx.x >> 6, lane = threadIdx.x & 63;
  const int l15 = lane & 15, g = lane >> 4;
  const int colf = wave * 32;
  const int rb = blk * 64;
  unsigned char* strip = OsRaw + wave * (16 * 144);
  const bool do1 = (o1v != nullptr);
  const bool hasbias = (bias0 != nullptr);

  short8 wf[2][2][4];
  const int slots[2] = { s0, s1 };
  #pragma unroll
  for (int m = 0; m < 2; ++m) {
    const unsigned short* wp = wT + (size_t)slots[m] * 16384;
    #pragma unroll
    for (int cb = 0; cb < 2; ++cb) {
      const int col = colf + cb * 16 + l15;
      #pragma unroll
      for (int kt = 0; kt < 4; ++kt)
        wf[m][cb][kt] = *(const short8*)(wp + (size_t)col * 128 + kt * 32 + g * 8);
    }
  }
  float bia[2][2][4];
  if (hasbias) {
    const float* bp[2] = { bias0, bias1 };
    #pragma unroll
    for (int m = 0; m < 2; ++m)
      #pragma unroll
      for (int cb = 0; cb < 2; ++cb)
        #pragma unroll
        for (int j = 0; j < 4; ++j)
          bia[m][cb][j] = bp[m][colf + cb * 16 + g * 4 + j];
  } else {
    #pragma unroll
    for (int m = 0; m < 2; ++m)
      #pragma unroll
      for (int cb = 0; cb < 2; ++cb)
        #pragma unroll
        for (int j = 0; j < 4; ++j)
          bia[m][cb][j] = 0.f;
  }

  // --- cooperative stage, lane-contiguous global reads ---
  if (abf16) {
    #pragma unroll
    for (int it = 0; it < 4; ++it) {
      const int c = it * 256 + threadIdx.x;
      const int row = c >> 4, cw = c & 15;
      const int gr = rb + row;
      const int ar = (gr < M) ? gr : (M - 1);
      short8 vch = *(const short8*)((const unsigned short*)Ap + (size_t)ar * 128 + cw * 8);
      *(short8*)(As + row * 136 + cw * 8) = vch;
    }
  } else {
    #pragma unroll
    for (int it = 0; it < 8; ++it) {
      const int c = it * 256 + threadIdx.x;
      const int row = c >> 5, cw = c & 31;
      const int gr = rb + row;
      const int ar = (gr < M) ? gr : (M - 1);
      const float4 f = *(const float4*)((const float*)Ap + (size_t)ar * 128 + cw * 4);
      uint2 pk;
      pk.x = (unsigned int)f2bf(f.x) | ((unsigned int)f2bf(f.y) << 16);
      pk.y = (unsigned int)f2bf(f.z) | ((unsigned int)f2bf(f.w) << 16);
      *(uint2*)(As + row * 136 + cw * 4) = pk;
    }
  }
  __syncthreads();

  const int srow = rb + l15;

  #pragma unroll
  for (int rg = 0; rg < 4; ++rg) {
    const int row = rg * 16 + l15;
    short8 a[4];
    #pragma unroll
    for (int kt = 0; kt < 4; ++kt)
      a[kt] = *(const short8*)(As + row * 136 + kt * 32 + g * 8);

    const int r = srow + rg * 16;

    #pragma unroll
    for (int m = 0; m < 2; ++m) {
      if (m == 1 && !do1) break;
      #pragma unroll
      for (int cb = 0; cb < 2; ++cb) {
        f32x4 acc; acc[0] = 0.f; acc[1] = 0.f; acc[2] = 0.f; acc[3] = 0.f;
        #pragma unroll
        for (int kt = 0; kt < 4; ++kt)
          acc = __builtin_amdgcn_mfma_f32_16x16x32_bf16(wf[m][cb][kt], a[kt], acc, 0, 0, 0);
        acc[0] += bia[m][cb][0];
        acc[1] += bia[m][cb][1];
        acc[2] += bia[m][cb][2];
        acc[3] += bia[m][cb][3];
        *(f32x4*)(strip + l15 * 144 + (cb * 16 + g * 4) * 4) = acc;
      }
      if (r < M) {
        const f32x4 lo = *(const f32x4*)(strip + l15 * 144 + (g * 8) * 4);
        const f32x4 hi = *(const f32x4*)(strip + l15 * 144 + (g * 8 + 4) * 4);
        const int fmt = (m == 0) ? F0 : F1;
        if (fmt) {
          uint2 pk8;
          pk8.x = pk4_fp8(lo[0], lo[1], lo[2], lo[3]);
          pk8.y = pk4_fp8(hi[0], hi[1], hi[2], hi[3]);
          unsigned char* op8 = (unsigned char*)((m == 0) ? o0v : o1v);
          *(uint2*)(op8 + (size_t)r * 128 + colf + g * 8) = pk8;
        } else {
          short8 vv;
          vv[0] = (short)f2bf(lo[0]); vv[1] = (short)f2bf(lo[1]);
          vv[2] = (short)f2bf(lo[2]); vv[3] = (short)f2bf(lo[3]);
          vv[4] = (short)f2bf(hi[0]); vv[5] = (short)f2bf(hi[1]);
          vv[6] = (short)f2bf(hi[2]); vv[7] = (short)f2bf(hi[3]);
          unsigned short* op = (unsigned short*)((m == 0) ? o0v : o1v);
          *(short8*)(op + (size_t)r * 128 + colf + g * 8) = vv;
        }
      }
    }
  }
}

// ================= merged launch: edge dual-GEMM (fp8) + L1 q(bf16)/k(fp8) + v(fp8)/xr(bf16) =================
__global__ __launch_bounds__(256, 4) void mega_l1(
    const float* __restrict__ ea, const float* __restrict__ x, const unsigned short* __restrict__ wT,
    const float* __restrict__ bq, const float* __restrict__ bk,
    const float* __restrict__ bv, const float* __restrict__ bs,
    unsigned char* __restrict__ e0, unsigned char* e1,
    unsigned short* __restrict__ q, unsigned char* __restrict__ k8,
    unsigned char* __restrict__ v8, unsigned short* __restrict__ xr,
    int ntile_e, int ntile_n)
{
  __shared__ __align__(16) unsigned short As[64 * 136];
  __shared__ __align__(16) unsigned char OsRaw[4 * 16 * 144];
  const int b = blockIdx.x;
  if (b < ntile_e) {
    gemm_body<1, 1>(ea, 0, wT, 8, 9, nullptr, nullptr, e0, e1, NE, b, As, OsRaw);
  } else if (b < ntile_e + ntile_n) {
    gemm_body<0, 1>(x, 0, wT, 0, 1, bq, bk, q, k8, NN, b - ntile_e, As, OsRaw);
  } else {
    gemm_body<1, 0>(x, 0, wT, 2, 3, bv, bs, v8, xr, NN, b - ntile_e - ntile_n, As, OsRaw);
  }
}

// ================= merged launch: both L2 qkvs GEMMs (bf16 input h1) =================
__global__ __launch_bounds__(256, 4) void mega_l2(
    const unsigned short* __restrict__ h1, const unsigned short* __restrict__ wT,
    const float* __restrict__ bq, const float* __restrict__ bk,
    const float* __restrict__ bv, const float* __restrict__ bs,
    unsigned short* __restrict__ q, unsigned char* __restrict__ k8,
    unsigned char* __restrict__ v8, unsigned short* __restrict__ xr,
    int ntile_n)
{
  __shared__ __align__(16) unsigned short As[64 * 136];
  __shared__ __align__(16) unsigned char OsRaw[4 * 16 * 144];
  const int b = blockIdx.x;
  if (b < ntile_n) {
    gemm_body<0, 1>(h1, 1, wT, 4, 5, bq, bk, q, k8, NN, b, As, OsRaw);
  } else {
    gemm_body<1, 0>(h1, 1, wT, 6, 7, bv, bs, v8, xr, NN, b - ntile_n, As, OsRaw);
  }
}

// ================= single edge GEMM (non-dual fallback, fp8 out, linear) =================
__global__ __launch_bounds__(256, 4) void edge_single(
    const float* __restrict__ ea, const unsigned short* __restrict__ wT, int slot,
    unsigned char* __restrict__ e0)
{
  __shared__ __align__(16) unsigned short As[64 * 136];
  __shared__ __align__(16) unsigned char OsRaw[4 * 16 * 144];
  gemm_body<1, 1>(ea, 0, wT, slot, slot, nullptr, nullptr, e0, nullptr, NE, blockIdx.x, As, OsRaw);
}

// ================= final GEMM + fused gate + epilogue (f32 out), 64 rows/block =================
__global__ __launch_bounds__(256, 2) void final_rs(
    const unsigned short* __restrict__ A, const unsigned short* __restrict__ wp,
    const float* __restrict__ bo, const float* __restrict__ xin,
    const float* __restrict__ Wg, const float* __restrict__ bg,
    float* __restrict__ out, int M)
{
  __shared__ float gl[4][64];
  __shared__ float grow_s[64];
  const int wave = threadIdx.x >> 6, lane = threadIdx.x & 63;
  const int l15 = lane & 15, g = lane >> 4;
  const int colf = wave * 32;
  const int rb = blockIdx.x * 64;

  short8 wf[2][4];
  #pragma unroll
  for (int cb = 0; cb < 2; ++cb) {
    const int col = colf + cb * 16 + l15;
    #pragma unroll
    for (int kt = 0; kt < 4; ++kt)
      wf[cb][kt] = *(const short8*)(wp + (size_t)col * 128 + kt * 32 + g * 8);
  }
  float bia[2][4], wgf[2][4];
  #pragma unroll
  for (int cb = 0; cb < 2; ++cb)
    #pragma unroll
    for (int j = 0; j < 4; ++j) {
      bia[cb][j] = bo[colf + cb * 16 + g * 4 + j];
      wgf[cb][j] = Wg[colf + cb * 16 + g * 4 + j];
    }

  f32x4 accs[4][2];
  float4 xv[4][2];

  #pragma unroll
  for (int rg = 0; rg < 4; ++rg) {
    const int r = rb + rg * 16 + l15;
    const int ar = (r < M) ? r : (M - 1);
    short8 a[4];
    #pragma unroll
    for (int kt = 0; kt < 4; ++kt)
      a[kt] = *(const short8*)(A + (size_t)ar * 128 + kt * 32 + g * 8);

    float part = 0.f;
    #pragma unroll
    for (int cb = 0; cb < 2; ++cb) {
      f32x4 acc; acc[0] = 0.f; acc[1] = 0.f; acc[2] = 0.f; acc[3] = 0.f;
      #pragma unroll
      for (int kt = 0; kt < 4; ++kt)
        acc = __builtin_amdgcn_mfma_f32_16x16x32_bf16(wf[cb][kt], a[kt], acc, 0, 0, 0);
      accs[rg][cb] = acc;
      const int c0 = colf + cb * 16 + g * 4;
      const float4 x4 = *(const float4*)(xin + (size_t)ar * 128 + c0);
      xv[rg][cb] = x4;
      part += x4.x * wgf[cb][0] + x4.y * wgf[cb][1] + x4.z * wgf[cb][2] + x4.w * wgf[cb][3];
    }
    part += __shfl_xor(part, 16, 64);
    part += __shfl_xor(part, 32, 64);
    if (g == 0) gl[wave][rg * 16 + l15] = part;
  }
  __syncthreads();
  if (threadIdx.x < 64) {
    const float s = gl[0][threadIdx.x] + gl[1][threadIdx.x] + gl[2][threadIdx.x] + gl[3][threadIdx.x] + bg[0];
    grow_s[threadIdx.x] = 1.f / (1.f + expf(-s));
  }
  __syncthreads();

  #pragma unroll
  for (int rg = 0; rg < 4; ++rg) {
    const int r = rb + rg * 16 + l15;
    if (r < M) {
      const float gr = grow_s[rg * 16 + l15];
      #pragma unroll
      for (int cb = 0; cb < 2; ++cb) {
        const int c0 = colf + cb * 16 + g * 4;
        const float4 x4 = xv[rg][cb];
        const f32x4 acc = accs[rg][cb];
        float4 res;
        res.x = gr * x4.x + (1.f - gr) * (acc[0] + bia[cb][0]);
        res.y = gr * x4.y + (1.f - gr) * (acc[1] + bia[cb][1]);
        res.z = gr * x4.z + (1.f - gr) * (acc[2] + bia[cb][2]);
        res.w = gr * x4.w + (1.f - gr) * (acc[3] + bia[cb][3]);
        *(float4*)(out + (size_t)r * 128 + c0) = res;
      }
    }
  }
}

// ================= fused CSR attention, 2 nodes/wave; k,v,e all fp8 (HW unpack) =================
__global__ __launch_bounds__(256) void csr_attn(
    const int* __restrict__ rowstart, const int* __restrict__ srcs, const int* __restrict__ eids,
    const unsigned char* __restrict__ e,    // edge-order fp8, 128 B/row
    const unsigned short* __restrict__ q,   // bf16
    const unsigned char* __restrict__ k8,   // fp8, 128 B/row
    const unsigned char* __restrict__ v8,   // fp8, 128 B/row
    const unsigned short* __restrict__ xr,
    const float* __restrict__ Wb, const float* __restrict__ lng, const float* __restrict__ lnb,
    const unsigned short* __restrict__ prev, unsigned short* __restrict__ hout)
{
  const int n = blockIdx.x * 8 + (threadIdx.x >> 5);    // half-wave per node
  if (n >= NN) return;
  const int lh = threadIdx.x & 31;                      // lane within half
  const int d0 = lh * 4;                                // 4 dims per lane
  const size_t base = (size_t)n * 128 + d0;

  const uint2 qp = *(const uint2*)(q + base);
  const float q0 = bf2f(qp.x & 0xffff), q1 = bf2f(qp.x >> 16);
  const float q2 = bf2f(qp.y & 0xffff), q3 = bf2f(qp.y >> 16);

  float a0 = 0.f, a1 = 0.f, a2 = 0.f, a3 = 0.f, den = 0.f;
  const int s = rowstart[n], eend = rowstart[n + 1];
  const float scale = 0.17677669529663687f;   // 1/sqrt(32)

  int pos = s;
  for (; pos + 3 < eend; pos += 4) {
    const int s0_ = srcs[pos], s1_ = srcs[pos + 1], s2_ = srcs[pos + 2], s3_ = srcs[pos + 3];
    const int t0_ = eids[pos], t1_ = eids[pos + 1], t2_ = eids[pos + 2], t3_ = eids[pos + 3];
    const unsigned int kp0 = *(const unsigned int*)(k8 + (size_t)s0_ * 128 + d0);
    const unsigned int kp1 = *(const unsigned int*)(k8 + (size_t)s1_ * 128 + d0);
    const unsigned int kp2 = *(const unsigned int*)(k8 + (size_t)s2_ * 128 + d0);
    const unsigned int kp3 = *(const unsigned int*)(k8 + (size_t)s3_ * 128 + d0);
    const unsigned int ep0 = *(const unsigned int*)(e + (size_t)t0_ * 128 + d0);
    const unsigned int ep1 = *(const unsigned int*)(e + (size_t)t1_ * 128 + d0);
    const unsigned int ep2 = *(const unsigned int*)(e + (size_t)t2_ * 128 + d0);
    const unsigned int ep3 = *(const unsigned int*)(e + (size_t)t3_ * 128 + d0);
    const unsigned int vp0 = *(const unsigned int*)(v8 + (size_t)s0_ * 128 + d0);
    const unsigned int vp1 = *(const unsigned int*)(v8 + (size_t)s1_ * 128 + d0);
    const unsigned int vp2 = *(const unsigned int*)(v8 + (size_t)s2_ * 128 + d0);
    const unsigned int vp3 = *(const unsigned int*)(v8 + (size_t)s3_ * 128 + d0);

    float e00, e01, e02, e03, e10, e11, e12, e13;
    float e20, e21, e22, e23, e30, e31, e32, e33;
    upk4_fp8(ep0, e00, e01, e02, e03);
    upk4_fp8(ep1, e10, e11, e12, e13);
    upk4_fp8(ep2, e20, e21, e22, e23);
    upk4_fp8(ep3, e30, e31, e32, e33);

    float k00, k01, k02, k03, k10, k11, k12, k13;
    float k20, k21, k22, k23, k30, k31, k32, k33;
    upk4_fp8(kp0, k00, k01, k02, k03);
    upk4_fp8(kp1, k10, k11, k12, k13);
    upk4_fp8(kp2, k20, k21, k22, k23);
    upk4_fp8(kp3, k30, k31, k32, k33);

    float d0_ = q0 * (k00 + e00) + q1 * (k01 + e01) + q2 * (k02 + e02) + q3 * (k03 + e03);
    float d1_ = q0 * (k10 + e10) + q1 * (k11 + e11) + q2 * (k12 + e12) + q3 * (k13 + e13);
    float d2_ = q0 * (k20 + e20) + q1 * (k21 + e21) + q2 * (k22 + e22) + q3 * (k23 + e23);
    float d3_ = q0 * (k30 + e30) + q1 * (k31 + e31) + q2 * (k32 + e32) + q3 * (k33 + e33);

    d0_ += __shfl_xor(d0_, 1, 64); d1_ += __shfl_xor(d1_, 1, 64);
    d2_ += __shfl_xor(d2_, 1, 64); d3_ += __shfl_xor(d3_, 1, 64);
    d0_ += __shfl_xor(d0_, 2, 64); d1_ += __shfl_xor(d1_, 2, 64);
    d2_ += __shfl_xor(d2_, 2, 64); d3_ += __shfl_xor(d3_, 2, 64);
    d0_ += __shfl_xor(d0_, 4, 64); d1_ += __shfl_xor(d1_, 4, 64);
    d2_ += __shfl_xor(d2_, 4, 64); d3_ += __shfl_xor(d3_, 4, 64);

    const float p0 = expf(d0_ * scale);
    const float p1 = expf(d1_ * scale);
    const float p2 = expf(d2_ * scale);
    const float p3 = expf(d3_ * scale);

    float w00, w01, w02, w03, w10, w11, w12, w13;
    float w20, w21, w22, w23, w30, w31, w32, w33;
    upk4_fp8(vp0, w00, w01, w02, w03);
    upk4_fp8(vp1, w10, w11, w12, w13);
    upk4_fp8(vp2, w20, w21, w22, w23);
    upk4_fp8(vp3, w30, w31, w32, w33);

    a0 += p0 * (w00 + e00) + p1 * (w10 + e10) + p2 * (w20 + e20) + p3 * (w30 + e30);
    a1 += p0 * (w01 + e01) + p1 * (w11 + e11) + p2 * (w21 + e21) + p3 * (w31 + e31);
    a2 += p0 * (w02 + e02) + p1 * (w12 + e12) + p2 * (w22 + e22) + p3 * (w32 + e32);
    a3 += p0 * (w03 + e03) + p1 * (w13 + e13) + p2 * (w23 + e23) + p3 * (w33 + e33);
    den += (p0 + p1) + (p2 + p3);
  }
  for (; pos < eend; ++pos) {
    const int sA = srcs[pos];
    const int tA = eids[pos];
    const unsigned int kpA = *(const unsigned int*)(k8 + (size_t)sA * 128 + d0);
    const unsigned int epA = *(const unsigned int*)(e + (size_t)tA * 128 + d0);
    const unsigned int vpA = *(const unsigned int*)(v8 + (size_t)sA * 128 + d0);
    float eA0, eA1, eA2, eA3, kA0, kA1, kA2, kA3, wA0, wA1, wA2, wA3;
    upk4_fp8(epA, eA0, eA1, eA2, eA3);
    upk4_fp8(kpA, kA0, kA1, kA2, kA3);
    upk4_fp8(vpA, wA0, wA1, wA2, wA3);
    float dA = q0 * (kA0 + eA0) + q1 * (kA1 + eA1) + q2 * (kA2 + eA2) + q3 * (kA3 + eA3);
    dA += __shfl_xor(dA, 1, 64);
    dA += __shfl_xor(dA, 2, 64);
    dA += __shfl_xor(dA, 4, 64);
    const float pA = expf(dA * scale);
    a0 += pA * (wA0 + eA0);
    a1 += pA * (wA1 + eA1);
    a2 += pA * (wA2 + eA2);
    a3 += pA * (wA3 + eA3);
    den += pA;
  }

  const float dinv = 1.f / (den + 1e-16f);
  const float o0 = a0 * dinv, o1 = a1 * dinv, o2 = a2 * dinv, o3 = a3 * dinv;

  const uint2 xp = *(const uint2*)(xr + base);
  const float x0 = bf2f(xp.x & 0xffff), x1 = bf2f(xp.x >> 16);
  const float x2 = bf2f(xp.y & 0xffff), x3 = bf2f(xp.y >> 16);

  const float4 wb0 = *(const float4*)(Wb + d0);
  const float4 wb1 = *(const float4*)(Wb + 128 + d0);
  const float4 wb2 = *(const float4*)(Wb + 256 + d0);
  float sb = o0 * wb0.x + o1 * wb0.y + o2 * wb0.z + o3 * wb0.w
           + x0 * wb1.x + x1 * wb1.y + x2 * wb1.z + x3 * wb1.w
           + (o0 - x0) * wb2.x + (o1 - x1) * wb2.y + (o2 - x2) * wb2.z + (o3 - x3) * wb2.w;
  #pragma unroll
  for (int off = 16; off >= 1; off >>= 1) sb += __shfl_xor(sb, off, 64);
  const float beta = 1.f / (1.f + expf(-sb));

  float y0 = beta * x0 + (1.f - beta) * o0;
  float y1 = beta * x1 + (1.f - beta) * o1;
  float y2 = beta * x2 + (1.f - beta) * o2;
  float y3 = beta * x3 + (1.f - beta) * o3;
  y0 = 0.5f * y0 * (1.f + erff(y0 * 0.7071067811865475f));
  y1 = 0.5f * y1 * (1.f + erff(y1 * 0.7071067811865475f));
  y2 = 0.5f * y2 * (1.f + erff(y2 * 0.7071067811865475f));
  y3 = 0.5f * y3 * (1.f + erff(y3 * 0.7071067811865475f));

  float mu = (y0 + y1) + (y2 + y3);
  #pragma unroll
  for (int off = 16; off >= 1; off >>= 1) mu += __shfl_xor(mu, off, 64);
  mu *= (1.f / 128.f);
  const float dv0 = y0 - mu, dv1 = y1 - mu, dv2 = y2 - mu, dv3 = y3 - mu;
  float var = (dv0 * dv0 + dv1 * dv1) + (dv2 * dv2 + dv3 * dv3);
  #pragma unroll
  for (int off = 16; off >= 1; off >>= 1) var += __shfl_xor(var, off, 64);
  var *= (1.f / 128.f);
  const float rs = rsqrtf(var + 1e-5f);

  const float4 lg = *(const float4*)(lng + d0);
  const float4 lb = *(const float4*)(lnb + d0);
  float h0 = dv0 * rs * lg.x + lb.x;
  float h1 = dv1 * rs * lg.y + lb.y;
  float h2 = dv2 * rs * lg.z + lb.z;
  float h3 = dv3 * rs * lg.w + lb.w;
  if (prev) {
    const uint2 pp = *(const uint2*)(prev + base);
    h0 += bf2f(pp.x & 0xffff); h1 += bf2f(pp.x >> 16);
    h2 += bf2f(pp.y & 0xffff); h3 += bf2f(pp.y >> 16);
  }
  uint2 packed;
  packed.x = (unsigned int)f2bf(h0) | ((unsigned int)f2bf(h1) << 16);
  packed.y = (unsigned int)f2bf(h2) | ((unsigned int)f2bf(h3) << 16);
  *(uint2*)(hout + base) = packed;
}

extern "C" void kernel_launch(void* const* d_in, const int* in_sizes, int n_in,
                              void* d_out, int out_size, void* d_ws, size_t ws_size,
                              hipStream_t stream)
{
  const float* x  = (const float*)d_in[0];
  const int*   ei = (const int*)d_in[1];
  const float* ea = (const float*)d_in[2];
  const float* Wq = (const float*)d_in[3];
  const float* bq = (const float*)d_in[4];
  const float* Wk = (const float*)d_in[5];
  const float* bk = (const float*)d_in[6];
  const float* Wv = (const float*)d_in[7];
  const float* bv = (const float*)d_in[8];
  const float* We = (const float*)d_in[9];
  const float* Ws = (const float*)d_in[10];
  const float* bs = (const float*)d_in[11];
  const float* Wb = (const float*)d_in[12];
  const float* lng= (const float*)d_in[13];
  const float* lnb= (const float*)d_in[14];
  const float* Wo = (const float*)d_in[15];
  const float* bo = (const float*)d_in[16];
  const float* Wg = (const float*)d_in[17];
  const float* bg = (const float*)d_in[18];
  float* outp = (float*)d_out;

  char* p = (char*)d_ws;
  auto take = [&](size_t b) -> char* { char* r = p; p += (b + 255) & ~(size_t)255; return r; };
  unsigned short* wT = (unsigned short*)take((size_t)11 * 16384 * 2);
  unsigned short* q  = (unsigned short*)take((size_t)NN * 128 * 2);
  unsigned char* k8  = (unsigned char*)take((size_t)NN * 128);
  unsigned char* v8  = (unsigned char*)take((size_t)NN * 128);
  unsigned short* xr = (unsigned short*)take((size_t)NN * 128 * 2);
  unsigned short* h1 = (unsigned short*)take((size_t)NN * 128 * 2);
  unsigned short* hs = (unsigned short*)take((size_t)NN * 128 * 2);
  int* deg      = (int*)take((size_t)NN * 4);
  int* rowstart = (int*)take((size_t)(NN + 1) * 4);
  int* cursor   = (int*)take((size_t)NN * 4);
  int* bsum     = (int*)take((size_t)128 * 4);
  int* srcs     = (int*)take((size_t)NE * 4);
  int* eids     = (int*)take((size_t)NE * 4);
  unsigned char* e0 = (unsigned char*)take((size_t)NE * 128);     // fp8: 1 B/elem
  size_t used = (size_t)(p - (char*)d_ws);
  const bool dual = (used + (size_t)NE * 128 <= ws_size);
  unsigned char* e1 = dual ? (unsigned char*)take((size_t)NE * 128) : e0;

  const int SCAN_BLOCKS = (NN + 1023) / 1024;   // 98
  const int NTILE_E  = (NE + 63) / 64;          // 12500
  const int NTILE_N  = (NN + 63) / 64;          // 1563
  const int NTILE_A  = (NN + 7) / 8;            // 12500

  // ---- CSR build ----
  hipMemsetAsync(deg, 0, (size_t)NN * 4, stream);
  hist_k<<<(NE + 255) / 256, 256, 0, stream>>>(ei, deg);
  scan1<<<SCAN_BLOCKS, 256, 0, stream>>>(deg, bsum);
  scan2<<<1, 64, 0, stream>>>(bsum, SCAN_BLOCKS, rowstart);
  scan3<<<SCAN_BLOCKS, 256, 0, stream>>>(deg, bsum, rowstart, cursor);
  scatter_k<<<(NE + 255) / 256, 256, 0, stream>>>(ei, cursor, srcs, eids);

  // ---- weights ----
  conv_w<<<704, 256, 0, stream>>>(Wq, Wk, Wv, Ws, We, Wo, wT);

  // ---- merged: edge projection (linear fp8) + L1 qkvs (k,v fp8) ----
  mega_l1<<<NTILE_E + 2 * NTILE_N, 256, 0, stream>>>(
      ea, x, wT, bq, bk, bv, bs,
      e0, dual ? e1 : nullptr, q, k8, v8, xr, NTILE_E, NTILE_N);
  csr_attn<<<NTILE_A, 256, 0, stream>>>(rowstart, srcs, eids, e0, q, k8, v8, xr, Wb, lng, lnb, nullptr, h1);

  // ---- layer 2 ----
  if (!dual) edge_single<<<NTILE_E, 256, 0, stream>>>(ea, wT, 9, e0);
  mega_l2<<<2 * NTILE_N, 256, 0, stream>>>(h1, wT, bq + 128, bk + 128, bv + 128, bs + 128, q, k8, v8, xr, NTILE_N);
  csr_attn<<<NTILE_A, 256, 0, stream>>>(rowstart, srcs, eids, dual ? e1 : e0, q, k8, v8, xr,
                                        Wb + 384, lng + 128, lnb + 128, h1, hs);

  // ---- final (gate fused) ----
  final_rs<<<NTILE_N, 256, 0, stream>>>(hs, wT + (size_t)10 * 16384, bo, x, Wg, bg, outp, NN);
}